// Round 11
// baseline (373.365 us; speedup 1.0000x reference)
//
#include <hip/hip_runtime.h>

#define N_TOT 10000
#define CLS_P 1000
#define NC 10
#define D 1024

#define TMI 256           // block tile rows (i)
#define TMJ 128           // block tile cols (j)
#define DELTA 1.35e-5f
#define INV_SCALE2 4.8828125e-4f   // 2 / 4096  (Xh stores 64*x; acc = 4096*dot)
#define ESC_CAP (1 << 22)
#define ESC_LOC 512
#define KCHUNKS (D / 32)
#define NTI ((N_TOT + TMI - 1) / TMI)   // 40
#define NTJ ((N_TOT + TMJ - 1) / TMJ)   // 79

typedef _Float16 f16x8 __attribute__((ext_vector_type(8)));
typedef float f32x4 __attribute__((ext_vector_type(4)));
typedef const __attribute__((address_space(1))) unsigned int* gptr_t;
typedef __attribute__((address_space(3))) unsigned int* lptr_t;

// ---------------- zero output + escalation counter ----------------
__global__ void zero_kernel(int* __restrict__ out, int n, int* __restrict__ esc_cnt) {
    int i = blockIdx.x * blockDim.x + threadIdx.x;
    if (i < n) out[i] = 0;
    if (i == 0) *esc_cnt = 0;
}

// ---------------- gather + fp16(64x) + fp64 norms ----------------
__global__ void prep_kernel(const float* __restrict__ feats, const int* __restrict__ ids,
                            unsigned short* __restrict__ Xh,
                            double* __restrict__ sqd, float* __restrict__ sqf) {
    int row = blockIdx.x;
    int id = ids[row];
    const float4* rp = (const float4*)(feats + (size_t)id * D);
    float4 v = rp[threadIdx.x];  // 256 threads * 4 = 1024
    float f[4] = {v.x, v.y, v.z, v.w};
    ushort4 hv;
    unsigned short* hp = &hv.x;
    double s = 0.0;
    #pragma unroll
    for (int e = 0; e < 4; e++) {
        s += (double)f[e] * f[e];
        union { _Float16 h; unsigned short u; } cv;
        cv.h = (_Float16)(f[e] * 64.0f);   // RNE; x64 avoids fp16 denormals
        hp[e] = cv.u;
    }
    *(ushort4*)(Xh + (size_t)row * D + threadIdx.x * 4) = hv;

    #pragma unroll
    for (int off = 32; off > 0; off >>= 1)
        s += __shfl_down(s, off, 64);
    __shared__ double wsum[4];
    int lane = threadIdx.x & 63, wv = threadIdx.x >> 6;
    if (lane == 0) wsum[wv] = s;
    __syncthreads();
    if (threadIdx.x == 0) {
        double t = wsum[0] + wsum[1] + wsum[2] + wsum[3];
        sqd[row] = t;
        sqf[row] = (float)t;
    }
}

// ---------------- fp16 MFMA pairwise count, 256x128 tile (3-buf async) ----------------
__launch_bounds__(256, 2)
__global__ void count_kernel(const unsigned short* __restrict__ Xh,
                             const float* __restrict__ sqf,
                             int* __restrict__ counts,
                             int* __restrict__ esc_cnt, int2* __restrict__ esc_list) {
    const int tjt = blockIdx.x;             // j-tile 0..78
    const int tit = blockIdx.y;             // i-tile 0..39
    if (tjt < 2 * tit) return;              // each unordered pair in exactly one block
    const int ib = tit * TMI, jb = tjt * TMJ;

    // skip tiles that are entirely same-class
    {
        int ihi = ib + TMI - 1; if (ihi > N_TOT - 1) ihi = N_TOT - 1;
        int jhi = jb + TMJ - 1; if (jhi > N_TOT - 1) jhi = N_TOT - 1;
        int ci0 = ib / CLS_P, ci1 = ihi / CLS_P;
        int cj0 = jb / CLS_P, cj1 = jhi / CLS_P;
        if (ci0 == ci1 && cj0 == cj1 && ci0 == cj0) return;
    }

    // 3 buffers x (A 16KB + B 8KB) = 72 KB; per-buffer halves: A rows [0,256) at r*32+slot*8, B at +8192
    __shared__ unsigned short S[3 * 12288];
    __shared__ int cred_i[TMI], cred_j[TMJ];
    __shared__ int esc_n, esc_base;
    __shared__ int2 esc_buf[ESC_LOC];

    const int tid = threadIdx.x;
    const int lane = tid & 63, w = tid >> 6;
    const int wi = w * 64;                   // this wave's i-strip within tile
    const int quad = lane >> 4, col = lane & 15;

    if (tid == 0) esc_n = 0;

    // staging: each wave: 4 A-calls (rows w*64+c*16) + 2 B-calls (rows w*32+c*16)
    const int rl0 = lane >> 2;      // 0..15 row within 16-row call group
    const int slot = lane & 3;      // dest k-slot
    const int q = (slot - rl0 - (rl0 >> 2)) & 3;   // source k-quarter (swizzle)

    const unsigned short* srcA[4];
    const unsigned short* srcB[2];
    #pragma unroll
    for (int c = 0; c < 4; c++) {
        int r = ib + w * 64 + c * 16 + rl0;
        if (r > N_TOT - 1) r = N_TOT - 1;
        srcA[c] = Xh + (size_t)r * D + q * 8;
    }
    #pragma unroll
    for (int c = 0; c < 2; c++) {
        int r = jb + w * 32 + c * 16 + rl0;
        if (r > N_TOT - 1) r = N_TOT - 1;
        srcB[c] = Xh + (size_t)r * D + q * 8;
    }

#define STAGE(KC_, BUFBASE_)                                                     \
    {                                                                            \
        _Pragma("unroll")                                                        \
        for (int c = 0; c < 4; c++)                                              \
            __builtin_amdgcn_global_load_lds(                                    \
                (gptr_t)(srcA[c] + (KC_) * 32),                                  \
                (lptr_t)((BUFBASE_) + w * 2048 + c * 512), 16, 0, 0);            \
        _Pragma("unroll")                                                        \
        for (int c = 0; c < 2; c++)                                              \
            __builtin_amdgcn_global_load_lds(                                    \
                (gptr_t)(srcB[c] + (KC_) * 32),                                  \
                (lptr_t)((BUFBASE_) + 8192 + w * 1024 + c * 512), 16, 0, 0);     \
    }

#define FRAGS(BUFBASE_)                                                          \
    {                                                                            \
        _Pragma("unroll")                                                        \
        for (int t = 0; t < 4; t++) {                                            \
            int rA = wi + t * 16 + col;                                          \
            int sA = (quad + rA + (rA >> 2)) & 3;                                \
            ah[t] = *(const f16x8*)((BUFBASE_) + rA * 32 + sA * 8);              \
        }                                                                        \
        _Pragma("unroll")                                                        \
        for (int u = 0; u < 8; u++) {                                            \
            int rB = u * 16 + col;                                               \
            int sB = (quad + rB + (rB >> 2)) & 3;                                \
            bh[u] = *(const f16x8*)((BUFBASE_) + 8192 + rB * 32 + sB * 8);       \
        }                                                                        \
    }

#define MFMA32                                                                   \
    {                                                                            \
        _Pragma("unroll")                                                        \
        for (int it = 0; it < 4; it++)                                           \
            _Pragma("unroll")                                                    \
            for (int jt = 0; jt < 8; jt++)                                       \
                acc[it][jt] = __builtin_amdgcn_mfma_f32_16x16x32_f16(ah[it], bh[jt], acc[it][jt], 0, 0, 0); \
    }

    f32x4 acc[4][8];
    #pragma unroll
    for (int it = 0; it < 4; it++)
        #pragma unroll
        for (int jt = 0; jt < 8; jt++)
            acc[it][jt] = (f32x4){0.f, 0.f, 0.f, 0.f};

    f16x8 ah[4], bh[8];

    unsigned short* p0 = S;
    unsigned short* p1 = S + 12288;
    unsigned short* p2 = S + 24576;

    // prologue: kc0 -> p0, kc1 -> p1 (12 loads/wave in flight); retire kc0 only
    STAGE(0, p0);
    STAGE(1, p1);
    asm volatile("s_waitcnt vmcnt(6) lgkmcnt(0)\ns_barrier" ::: "memory");

    for (int kc = 0; kc < KCHUNKS; kc++) {
        if (kc + 2 < KCHUNKS) STAGE(kc + 2, p2);
        FRAGS(p0);
        // retire only the stage consumed NEXT iteration; newest stays in flight
        if (kc + 2 < KCHUNKS) {
            asm volatile("s_waitcnt vmcnt(6)\ns_barrier" ::: "memory");
        } else if (kc + 1 < KCHUNKS) {
            asm volatile("s_waitcnt vmcnt(0)\ns_barrier" ::: "memory");
        }
        MFMA32;
        unsigned short* t = p0; p0 = p1; p1 = p2; p2 = t;
    }

    // ---------------- epilogue: threshold + LDS-buffered escalate + symmetric reduce ----------------
    cred_i[tid] = 0;
    if (tid < TMJ) cred_j[tid] = 0;
    __syncthreads();

    const float thr_lo = 0.25f - DELTA;
    const float thr_hi = 0.25f + DELTA;

    float sqj[8];
    int clsj[8], jv[8], jidx[8];
    #pragma unroll
    for (int jt = 0; jt < 8; jt++) {
        int j = jb + jt * 16 + col;
        jidx[jt] = j;
        jv[jt] = (j < N_TOT);
        sqj[jt] = jv[jt] ? sqf[j] : 0.f;
        clsj[jt] = j / CLS_P;
    }

    int cj[8] = {0, 0, 0, 0, 0, 0, 0, 0};

    #pragma unroll
    for (int it = 0; it < 4; it++) {
        #pragma unroll
        for (int r = 0; r < 4; r++) {
            int irow = wi + it * 16 + quad * 4 + r;
            int i = ib + irow;
            bool iv = (i < N_TOT);
            float sqi = iv ? sqf[i] : 0.f;
            int clsi = i / CLS_P;
            int ci = 0;
            #pragma unroll
            for (int jt = 0; jt < 8; jt++) {
                int j = jidx[jt];
                bool ok = iv && jv[jt] && (clsj[jt] != clsi) && (j > i);
                float d2 = sqi + sqj[jt] - acc[it][jt][r] * INV_SCALE2;
                bool in = ok && (d2 < thr_lo);
                bool esc = ok && !in && (d2 < thr_hi);
                ci += in ? 1 : 0;
                cj[jt] += in ? 1 : 0;
                if (esc) {
                    int k = atomicAdd(&esc_n, 1);      // LDS atomic: fast
                    if (k < ESC_LOC) {
                        esc_buf[k] = make_int2(i, j);
                    } else {
                        int idx = atomicAdd(esc_cnt, 1);   // rare overflow path
                        if (idx < ESC_CAP) esc_list[idx] = make_int2(i, j);
                    }
                }
            }
            ci += __shfl_xor(ci, 1, 64);
            ci += __shfl_xor(ci, 2, 64);
            ci += __shfl_xor(ci, 4, 64);
            ci += __shfl_xor(ci, 8, 64);
            if (col == 0 && ci) atomicAdd(&cred_i[irow], ci);
        }
    }
    #pragma unroll
    for (int jt = 0; jt < 8; jt++) {
        int v = cj[jt];
        v += __shfl_xor(v, 16, 64);
        v += __shfl_xor(v, 32, 64);
        if (quad == 0 && v) atomicAdd(&cred_j[jt * 16 + col], v);
    }
    __syncthreads();
    {
        int i = ib + tid;
        if (i < N_TOT && cred_i[tid]) atomicAdd(&counts[i], cred_i[tid]);
        if (tid < TMJ) {
            int j = jb + tid;
            if (j < N_TOT && cred_j[tid]) atomicAdd(&counts[j], cred_j[tid]);
        }
    }
    // flush escalation buffer: ONE global atomic per block
    if (tid == 0) {
        int n = esc_n; if (n > ESC_LOC) n = ESC_LOC;
        esc_n = n;
        esc_base = atomicAdd(esc_cnt, n);
    }
    __syncthreads();
    for (int k = tid; k < esc_n; k += 256) {
        int idx = esc_base + k;
        if (idx < ESC_CAP) esc_list[idx] = esc_buf[k];
    }
}

// ---------------- fp64 exact recheck: 16 lanes per pair, 4 pairs per wave ----------------
__global__ void escalate_kernel(const float* __restrict__ feats, const int* __restrict__ ids,
                                const double* __restrict__ sqd,
                                const int* __restrict__ esc_cnt, const int2* __restrict__ esc_list,
                                int* __restrict__ counts) {
    int n = *esc_cnt;
    if (n > ESC_CAP) n = ESC_CAP;
    int lane = threadIdx.x & 63;
    int sub = lane >> 4;         // pair slot within wave
    int l16 = lane & 15;
    int wglob = (blockIdx.x * blockDim.x + threadIdx.x) >> 6;
    int W = (gridDim.x * blockDim.x) >> 6;
    for (int p0 = wglob * 4; p0 < n; p0 += W * 4) {
        int p = p0 + sub;
        bool act = (p < n);
        int2 pr = act ? esc_list[p] : make_int2(0, 0);
        const float* xi = feats + (size_t)ids[pr.x] * D;
        const float* xj = feats + (size_t)ids[pr.y] * D;
        double s = 0.0;
        int k0 = l16 * 64;
        #pragma unroll
        for (int k = 0; k < 64; k += 4) {
            float4 a = *(const float4*)(xi + k0 + k);
            float4 b = *(const float4*)(xj + k0 + k);
            s += (double)a.x * b.x + (double)a.y * b.y + (double)a.z * b.z + (double)a.w * b.w;
        }
        s += __shfl_xor(s, 1, 64);
        s += __shfl_xor(s, 2, 64);
        s += __shfl_xor(s, 4, 64);
        s += __shfl_xor(s, 8, 64);
        if (act && l16 == 0) {
            double d2 = sqd[pr.x] + sqd[pr.y] - 2.0 * s;
            if (d2 < 0.25) {
                atomicAdd(&counts[pr.x], 1);
                atomicAdd(&counts[pr.y], 1);
            }
        }
    }
}

// ---------------- stable-argsort selection (one thread per p) ----------------
__global__ void sel_kernel(const int* __restrict__ counts, const int* __restrict__ ids,
                           int* __restrict__ out_ids, int pcb) {
    int c = blockIdx.x;
    __shared__ int lc[CLS_P];
    for (int p = threadIdx.x; p < CLS_P; p += blockDim.x)
        lc[p] = counts[c * CLS_P + p];
    __syncthreads();
    int p = threadIdx.x;
    if (p < CLS_P) {
        int cp = lc[p];
        int rank = 0;
        for (int qq = 0; qq < CLS_P; qq++) {
            int cq = lc[qq];
            rank += (cq < cp) || (cq == cp && qq < p);
        }
        if (rank < pcb)
            out_ids[c * pcb + rank] = ids[c * CLS_P + p];
    }
}

extern "C" void kernel_launch(void* const* d_in, const int* in_sizes, int n_in,
                              void* d_out, int out_size, void* d_ws, size_t ws_size,
                              hipStream_t stream) {
    const float* feats = (const float*)d_in[0];
    const int* ids = (const int*)d_in[1];
    int budget = out_size - N_TOT;
    int pcb = budget / NC;  // 200
    int* out = (int*)d_out;
    int* counts_out = out + NC * pcb;

    char* ws = (char*)d_ws;
    const size_t XH_OFF = 0;
    const size_t SQD_OFF = XH_OFF + (size_t)N_TOT * D * 2;           // 20.48 MB
    const size_t SQF_OFF = SQD_OFF + (size_t)N_TOT * 8;
    const size_t ESCC_OFF = (SQF_OFF + (size_t)N_TOT * 4 + 63) & ~(size_t)63;
    const size_t ESCL_OFF = ESCC_OFF + 64;

    unsigned short* Xh = (unsigned short*)(ws + XH_OFF);
    double* sqd = (double*)(ws + SQD_OFF);
    float* sqf = (float*)(ws + SQF_OFF);
    int* esc_cnt = (int*)(ws + ESCC_OFF);
    int2* esc_list = (int2*)(ws + ESCL_OFF);

    zero_kernel<<<(out_size + 255) / 256, 256, 0, stream>>>(out, out_size, esc_cnt);
    prep_kernel<<<N_TOT, 256, 0, stream>>>(feats, ids, Xh, sqd, sqf);
    dim3 grid(NTJ, NTI);
    count_kernel<<<grid, 256, 0, stream>>>(Xh, sqf, counts_out, esc_cnt, esc_list);
    escalate_kernel<<<4096, 256, 0, stream>>>(feats, ids, sqd, esc_cnt, esc_list, counts_out);
    sel_kernel<<<NC, 1024, 0, stream>>>(counts_out, ids, out, pcb);
}